// Round 13
// baseline (199.078 us; speedup 1.0000x reference)
//
#include <hip/hip_runtime.h>

typedef unsigned short u16;
typedef unsigned int u32;
typedef float v4f __attribute__((ext_vector_type(4)));
typedef __bf16 bf16x8 __attribute__((ext_vector_type(8)));

// Problem constants: x (8, 768, 32x32), w_qkv (2304, 768), w_proj (768, 768)
#define BATCH 8
#define CDIM 768
#define NHEAD 12
#define DH 64
#define NSEQ 1024
// softmax scale folded with log2(e): logits * dh^-0.5 * log2e
#define SCL 0.18033688011112042f

__device__ __forceinline__ u16 f2bf(float f) {
  u32 u = __builtin_bit_cast(u32, f);
  u += 0x7fffu + ((u >> 16) & 1u);   // RNE
  return (u16)(u >> 16);
}

// round-half-up bf16 (same <=0.5ulp bound as RNE, 1 op + shared pack)
__device__ __forceinline__ u16 b16(float f) {
  return (u16)((__builtin_bit_cast(u32, f) + 0x8000u) >> 16);
}
// pack two floats -> {lo16=bf(lo), hi16=bf(hi)} via one v_perm_b32
__device__ __forceinline__ u32 pkbf(float hi, float lo) {
  u32 a = __builtin_bit_cast(u32, hi) + 0x8000u;
  u32 b = __builtin_bit_cast(u32, lo) + 0x8000u;
  return __builtin_amdgcn_perm(a, b, 0x07060302u);  // {a[31:16], b[31:16]}
}

__device__ __forceinline__ v4f mfma16(bf16x8 a, bf16x8 b, v4f c) {
  return __builtin_amdgcn_mfma_f32_16x16x32_bf16(a, b, c, 0, 0, 0);
}

// async global->LDS DMA, 16B per lane; LDS dest = wave-uniform base + lane*16
__device__ __forceinline__ void gload16(const u16* g, u16* l) {
  __builtin_amdgcn_global_load_lds(
      (const __attribute__((address_space(1))) void*)g,
      (__attribute__((address_space(3))) void*)l, 16, 0, 0);
}

// ------------- kernel: fused prep --------------------------------------
// blocks [0,1728): w_qkv fp32->bf16 ; [1728,2304): w_proj ; [2304,3840):
// x (b,c,p) -> xT (b,p,c) bf16 transpose. One launch instead of three.
__global__ __launch_bounds__(256) void k_prep(const float* __restrict__ x,
                                              const float* __restrict__ wq,
                                              const float* __restrict__ wp,
                                              u16* __restrict__ xT,
                                              u16* __restrict__ wqb,
                                              u16* __restrict__ wpb) {
  __shared__ u16 Ts[64][72];   // transpose staging; pitch 72 keeps 16B align
  int bid = blockIdx.x;
  int t = threadIdx.x;
  if (bid < 2304) {
    bool isQ = bid < 1728;
    const float* s = isQ ? wq : wp;
    u16* d = isQ ? wqb : wpb;
    int i = (isQ ? bid : bid - 1728) * 256 + t;   // exact coverage, no bounds
    float4 v = ((const float4*)s)[i];
    u32 lo = (u32)f2bf(v.x) | ((u32)f2bf(v.y) << 16);
    u32 hi = (u32)f2bf(v.z) | ((u32)f2bf(v.w) << 16);
    ((uint2*)d)[i] = uint2{lo, hi};
    return;
  }
  int id = bid - 2304;
  int p0 = (id & 15) * 64; id >>= 4;
  int c0 = (id % 12) * 64; int b = id / 12;
  int cr = t >> 4;             // 0..15
  int p4 = (t & 15) * 4;       // 0..60
  const float* src = x + ((size_t)b * CDIM + c0) * NSEQ + p0;
#pragma unroll
  for (int i = 0; i < 4; ++i) {
    int c = cr + i * 16;
    float4 v = *(const float4*)&src[(size_t)c * NSEQ + p4];
    Ts[p4 + 0][c] = f2bf(v.x);
    Ts[p4 + 1][c] = f2bf(v.y);
    Ts[p4 + 2][c] = f2bf(v.z);
    Ts[p4 + 3][c] = f2bf(v.w);
  }
  __syncthreads();
  int p = t >> 2;              // 0..63
  int cq = t & 3;
  u16* dst = xT + ((size_t)b * NSEQ + p0 + p) * CDIM + c0;
#pragma unroll
  for (int j = 0; j < 2; ++j) {
    int ch = cq + j * 4;       // 8 chunks of 8 bf16 = 64 elems
    *(int4*)&dst[ch * 8] = *(const int4*)&Ts[p][ch * 8];
  }
}

// ------------- kernel: QKV GEMM  D[o][p] = sum_c W[o][c] * xT[p][c] -----
// 128x128 tile, 256 thr, BK=64 single-buffer: HALF the barrier periods
// (12 vs 24) with double the MFMA per period — attacks the fixed
// per-period overhead that R10-R12 showed is the binding cost (every
// pipe 20-30% busy, intra-block pipelining and occupancy both neutral).
// K stored SPLIT-HALF (As[half][128*32], pitch 64B) so the DMA layout and
// the bank-conflict-free b128 frag reads stay identical to the proven
// m97 geometry; LDS stays 32 KB (m132's BK=128 died at 64 KB).
// Deterministic two-barrier sync (round-10 pattern).
// Q,K rows (o<1536) stored transposed qkT[b][p][o]; V rows to vbuf[b][d][p].
__global__ __launch_bounds__(256) void k_gemm_qkv(const u16* __restrict__ Wb,
                                                  const u16* __restrict__ xT,
                                                  u16* __restrict__ qkT,
                                                  u16* __restrict__ vbuf) {
  int oT = blockIdx.x * 128, pT = blockIdx.y * 128, b = blockIdx.z;
  __shared__ u16 As[2][128 * 32];   // [k-half][row*32+col] 16 KB
  __shared__ u16 Bs[2][128 * 32];   // 16 KB
  int t = threadIdx.x, lane = t & 63, wid = t >> 6;
  int ln = lane & 15, quad = lane >> 4;
  int wr = wid >> 1, wc = wid & 1;
  v4f acc[4][4] = {};

  // DMA staging: wave wid covers 16-row slabs at wid*16 and wid*16+64,
  // for each of the two 32-wide k-halves. lane i -> row +i/4, chunk (i%4)*8.
  int lr = lane >> 2, lc = (lane & 3) * 8;
  const u16* Ag = Wb + (size_t)(oT + wid * 16 + lr) * CDIM + lc;
  const u16* Bg = xT + ((size_t)b * NSEQ + pT + wid * 16 + lr) * CDIM + lc;
  int s0 = (wid * 16) * 32, s1 = (wid * 16 + 64) * 32;

  for (int kk = 0; kk < CDIM; kk += 64) {
    __syncthreads();   // all waves done reading previous slab
    gload16(Ag + kk, &As[0][s0]);
    gload16(Ag + (size_t)64 * CDIM + kk, &As[0][s1]);
    gload16(Ag + kk + 32, &As[1][s0]);
    gload16(Ag + (size_t)64 * CDIM + kk + 32, &As[1][s1]);
    gload16(Bg + kk, &Bs[0][s0]);
    gload16(Bg + (size_t)64 * CDIM + kk, &Bs[0][s1]);
    gload16(Bg + kk + 32, &Bs[1][s0]);
    gload16(Bg + (size_t)64 * CDIM + kk + 32, &Bs[1][s1]);
    __syncthreads();   // drains vmcnt (DMA) -> slab resident

    bf16x8 af0[4], af1[4], bf0[4], bf1[4];
#pragma unroll
    for (int mt = 0; mt < 4; ++mt) {
      af0[mt] = *(const bf16x8*)&As[0][(wr * 64 + mt * 16 + ln) * 32 + quad * 8];
      af1[mt] = *(const bf16x8*)&As[1][(wr * 64 + mt * 16 + ln) * 32 + quad * 8];
    }
#pragma unroll
    for (int nt = 0; nt < 4; ++nt) {
      bf0[nt] = *(const bf16x8*)&Bs[0][(wc * 64 + nt * 16 + ln) * 32 + quad * 8];
      bf1[nt] = *(const bf16x8*)&Bs[1][(wc * 64 + nt * 16 + ln) * 32 + quad * 8];
    }
#pragma unroll
    for (int mt = 0; mt < 4; ++mt)
#pragma unroll
      for (int nt = 0; nt < 4; ++nt) {
        acc[mt][nt] = mfma16(af0[mt], bf0[nt], acc[mt][nt]);
        acc[mt][nt] = mfma16(af1[mt], bf1[nt], acc[mt][nt]);
      }
  }

  bool isV = (oT >= 2 * CDIM);
#pragma unroll
  for (int mt = 0; mt < 4; ++mt) {
#pragma unroll
    for (int nt = 0; nt < 4; ++nt) {
      int ro = oT + wr * 64 + mt * 16 + quad * 4;   // 4 consecutive o rows
      int cp = pT + wc * 64 + nt * 16 + ln;
      if (!isV) {
        u32 lo = (u32)f2bf(acc[mt][nt][0]) | ((u32)f2bf(acc[mt][nt][1]) << 16);
        u32 hi = (u32)f2bf(acc[mt][nt][2]) | ((u32)f2bf(acc[mt][nt][3]) << 16);
        *(uint2*)&qkT[((size_t)b * NSEQ + cp) * 1536 + ro] = uint2{lo, hi};
      } else {
#pragma unroll
        for (int r = 0; r < 4; ++r)
          vbuf[((size_t)b * CDIM + (ro - 2 * CDIM + r)) * NSEQ + cp] =
              f2bf(acc[mt][nt][r]);
      }
    }
  }
}

// ------------- kernel: flash attention (v6, round-10 verbatim) ----------
// 256 thr / 4 waves, 128 queries/block, grid 768 = exactly 3 blocks/CU,
// XCD decode (id%8 = b) keeps each batch's K+V in its XCD L2.
// K/V slabs staged via global_load_lds DMA into split-half [64][32] LDS,
// SINGLE-buffered with __syncthreads.
__global__ __launch_bounds__(256) void k_attn(const u16* __restrict__ qkT,
                                              const u16* __restrict__ vbuf,
                                              u16* __restrict__ attnT) {
  int id = blockIdx.x;
  int b = id & 7;              // XCD slot under flat%8 round-robin
  int j = id >> 3;             // 0..95
  int h = j % 12;
  int nt0 = (j / 12) * 128;

  int t = threadIdx.x, lane = t & 63, wid = t >> 6;
  int ln = lane & 15, quad = lane >> 4;
  int nbase = nt0 + wid * 32;

  __shared__ u16 Ks[2][64 * 32];   // [32-col half][row*32+col]  8 KB
  __shared__ u16 Vs[2][64 * 32];   //  8 KB
  __shared__ u16 Pa[4][32 * 72];   // per wave: [n][m], pitch 72; 18 KB
  u16* myP = Pa[wid];

  // Q frags (B operand of S^T): B[col=n][k]; once per kernel
  const u16* qbase = qkT + ((size_t)b * NSEQ + nbase) * 1536 + h * DH;
  bf16x8 aq[2][2];
#pragma unroll
  for (int mt = 0; mt < 2; ++mt)
#pragma unroll
    for (int ks = 0; ks < 2; ++ks)
      aq[mt][ks] = *(const bf16x8*)&qbase[(size_t)(mt * 16 + ln) * 1536 + ks * 32 + quad * 8];

  bf16x8 ones;
#pragma unroll
  for (int i = 0; i < 8; ++i) ones[i] = __builtin_bit_cast(__bf16, (u16)0x3F80);

  v4f oacc[2][4] = {};
  v4f lacc[2] = {};

  // DMA staging: wave wid covers rows wid*16..wid*16+15 of the 64-key slab.
  // lane i -> row +i/4, u16 chunk (i%4)*8 within a 32-u16 half-row.
  int lr = lane >> 2, lc = (lane & 3) * 8;
  const u16* kgw = qkT + (size_t)b * NSEQ * 1536 + CDIM + h * DH +
                   (size_t)(wid * 16 + lr) * 1536 + lc;
  const u16* vgw = vbuf + ((size_t)b * CDIM + h * DH + wid * 16 + lr) * NSEQ + lc;
  int sb = (wid * 16) * 32;   // wave-uniform LDS slab base (u16 units)

  for (int s = 0; s < 16; ++s) {
    __syncthreads();            // all waves done reading prev slab
    size_t ko = (size_t)s * 64 * 1536;
    int vo = s * 64;
    gload16(kgw + ko, &Ks[0][sb]);
    gload16(kgw + ko + 32, &Ks[1][sb]);
    gload16(vgw + vo, &Vs[0][sb]);
    gload16(vgw + vo + 32, &Vs[1][sb]);
    __syncthreads();            // drains vmcnt -> slab resident for all waves

    // S^T tiles (rows=keys ct, cols=queries mt); p = exp2(s*SCL)
#pragma unroll
    for (int ct = 0; ct < 4; ++ct) {
      bf16x8 kf0 = *(const bf16x8*)&Ks[0][(ct * 16 + ln) * 32 + quad * 8];
      bf16x8 kf1 = *(const bf16x8*)&Ks[1][(ct * 16 + ln) * 32 + quad * 8];
#pragma unroll
      for (int mt = 0; mt < 2; ++mt) {
        v4f sc = {};
        sc = mfma16(kf0, aq[mt][0], sc);
        sc = mfma16(kf1, aq[mt][1], sc);
        float p0 = __builtin_amdgcn_exp2f(sc[0] * SCL);
        float p1 = __builtin_amdgcn_exp2f(sc[1] * SCL);
        float p2 = __builtin_amdgcn_exp2f(sc[2] * SCL);
        float p3 = __builtin_amdgcn_exp2f(sc[3] * SCL);
        // lane holds P[n=mt*16+ln][m=ct*16+quad*4 .. +3] -> one 8B store
        *(uint2*)&myP[(mt * 16 + ln) * 72 + ct * 16 + quad * 4] =
            uint2{pkbf(p1, p0), pkbf(p3, p2)};
      }
    }

    // PV + row-sum: A = P (row=n, k=m), B = V (col=d, k=m) / ones
    bf16x8 ap[2][2];
#pragma unroll
    for (int mt = 0; mt < 2; ++mt)
#pragma unroll
      for (int ks = 0; ks < 2; ++ks)
        ap[mt][ks] = *(const bf16x8*)&myP[(mt * 16 + ln) * 72 + ks * 32 + quad * 8];
#pragma unroll
    for (int mt = 0; mt < 2; ++mt) {
      lacc[mt] = mfma16(ap[mt][0], ones, lacc[mt]);
      lacc[mt] = mfma16(ap[mt][1], ones, lacc[mt]);
    }
#pragma unroll
    for (int nt = 0; nt < 4; ++nt) {
      bf16x8 vf0 = *(const bf16x8*)&Vs[0][(nt * 16 + ln) * 32 + quad * 8];
      bf16x8 vf1 = *(const bf16x8*)&Vs[1][(nt * 16 + ln) * 32 + quad * 8];
#pragma unroll
      for (int mt = 0; mt < 2; ++mt) {
        oacc[mt][nt] = mfma16(ap[mt][0], vf0, oacc[mt][nt]);
        oacc[mt][nt] = mfma16(ap[mt][1], vf1, oacc[mt][nt]);
      }
    }
  }

  // normalize (lacc C-layout == oacc C-layout) and store O as attnT[b][n][c]
#pragma unroll
  for (int mt = 0; mt < 2; ++mt) {
#pragma unroll
    for (int r = 0; r < 4; ++r) {
      float inv = 1.0f / lacc[mt][r];
      int n = nbase + mt * 16 + quad * 4 + r;
      u16* dst = attnT + ((size_t)b * NSEQ + n) * CDIM + h * DH;
#pragma unroll
      for (int nt = 0; nt < 4; ++nt)
        dst[nt * 16 + ln] = b16(oacc[mt][nt][r] * inv);
    }
  }
}

// ------------- kernel: proj GEMM  out[o][p] = sum_c Wp[o][c]*attnT[p][c] -
// Grid (b, oT, pT) b-fastest (L2-resident per-batch working set).
// Pipelined __syncthreads double-buffer (round-11 form).
__global__ __launch_bounds__(256) void k_gemm_proj(const u16* __restrict__ Wb,
                                                   const u16* __restrict__ aT,
                                                   float* __restrict__ out) {
  int b = blockIdx.x, oT = blockIdx.y * 128, pT = blockIdx.z * 128;
  __shared__ u16 As[2][128 * 32];   // 16 KB
  __shared__ u16 Bs[2][128 * 32];   // 16 KB
  int t = threadIdx.x, lane = t & 63, wid = t >> 6;
  int ln = lane & 15, quad = lane >> 4;
  int wr = wid >> 1, wc = wid & 1;
  v4f acc[4][4] = {};

  int lr = lane >> 2, lc = (lane & 3) * 8;
  const u16* Ag = Wb + (size_t)(oT + wid * 16 + lr) * CDIM + lc;
  const u16* Bg = aT + ((size_t)b * NSEQ + pT + wid * 16 + lr) * CDIM + lc;
  int a0 = (wid * 16) * 32, a1 = (wid * 16 + 64) * 32;

  // prologue: slab 0 -> buf 0, drain
  gload16(Ag, &As[0][a0]);
  gload16(Ag + (size_t)64 * CDIM, &As[0][a1]);
  gload16(Bg, &Bs[0][a0]);
  gload16(Bg + (size_t)64 * CDIM, &Bs[0][a1]);
  __syncthreads();

  for (int k = 0; k < 24; ++k) {
    int cur = k & 1, nxt = cur ^ 1;
    if (k < 23) {
      int kk = (k + 1) * 32;
      gload16(Ag + kk, &As[nxt][a0]);
      gload16(Ag + (size_t)64 * CDIM + kk, &As[nxt][a1]);
      gload16(Bg + kk, &Bs[nxt][a0]);
      gload16(Bg + (size_t)64 * CDIM + kk, &Bs[nxt][a1]);
    }
    bf16x8 af[4], bfr[4];
#pragma unroll
    for (int mt = 0; mt < 4; ++mt)
      af[mt] = *(const bf16x8*)&As[cur][(wr * 64 + mt * 16 + ln) * 32 + quad * 8];
#pragma unroll
    for (int nt = 0; nt < 4; ++nt)
      bfr[nt] = *(const bf16x8*)&Bs[cur][(wc * 64 + nt * 16 + ln) * 32 + quad * 8];
#pragma unroll
    for (int mt = 0; mt < 4; ++mt)
#pragma unroll
      for (int nt = 0; nt < 4; ++nt)
        acc[mt][nt] = mfma16(af[mt], bfr[nt], acc[mt][nt]);
    __syncthreads();   // drains slab k+1's DMA (hidden behind MFMA) + joins
  }

#pragma unroll
  for (int mt = 0; mt < 4; ++mt) {
#pragma unroll
    for (int nt = 0; nt < 4; ++nt) {
      int ro = oT + wr * 64 + mt * 16 + quad * 4;
      int cp = pT + wc * 64 + nt * 16 + ln;
#pragma unroll
      for (int r = 0; r < 4; ++r)
        out[((size_t)b * CDIM + ro + r) * NSEQ + cp] = acc[mt][nt][r];
    }
  }
}

extern "C" void kernel_launch(void* const* d_in, const int* in_sizes, int n_in,
                              void* d_out, int out_size, void* d_ws, size_t ws_size,
                              hipStream_t stream) {
  const float* x = (const float*)d_in[0];
  const float* w_qkv = (const float*)d_in[1];
  const float* w_proj = (const float*)d_in[2];
  float* out = (float*)d_out;

  char* ws = (char*)d_ws;
  // ws layout (bytes):
  //   wqkv_bf : 2304*768*2       = 3,538,944
  //   wproj_bf: 768*768*2        = 1,179,648
  //   xT      : 8*1024*768*2     = 12,582,912   (reused as attnT after GEMM1)
  //   vbuf    : 8*768*1024*2     = 12,582,912
  // qkT (8*1024*1536*2 = 25,165,824 B) aliases d_out (8*768*1024*4 = same size);
  // qkT is dead before k_gemm_proj writes d_out.
  u16* wqkv_bf = (u16*)(ws);
  u16* wproj_bf = (u16*)(ws + 3538944);
  u16* xT = (u16*)(ws + 4718592);
  u16* vbuf = (u16*)(ws + 17301504);
  u16* qkT = (u16*)d_out;
  u16* attnT = xT;

  k_prep<<<dim3(3840), dim3(256), 0, stream>>>(x, w_qkv, w_proj, xT, wqkv_bf, wproj_bf);
  k_gemm_qkv<<<dim3(18, 8, 8), dim3(256), 0, stream>>>(wqkv_bf, xT, qkT, vbuf);
  k_attn<<<dim3(768), dim3(256), 0, stream>>>(qkT, vbuf, attnT);
  k_gemm_proj<<<dim3(8, 6, 8), dim3(256), 0, stream>>>(wproj_bf, attnT, out);
}

// Round 14
// 194.890 us; speedup vs baseline: 1.0215x; 1.0215x over previous
//
#include <hip/hip_runtime.h>

typedef unsigned short u16;
typedef unsigned int u32;
typedef float v4f __attribute__((ext_vector_type(4)));
typedef __bf16 bf16x8 __attribute__((ext_vector_type(8)));

// Problem constants: x (8, 768, 32x32), w_qkv (2304, 768), w_proj (768, 768)
#define BATCH 8
#define CDIM 768
#define NHEAD 12
#define DH 64
#define NSEQ 1024
// softmax scale folded with log2(e): logits * dh^-0.5 * log2e
#define SCL 0.18033688011112042f

__device__ __forceinline__ u16 f2bf(float f) {
  u32 u = __builtin_bit_cast(u32, f);
  u += 0x7fffu + ((u >> 16) & 1u);   // RNE
  return (u16)(u >> 16);
}

// round-half-up bf16 (same <=0.5ulp bound as RNE, 1 op + shared pack)
__device__ __forceinline__ u16 b16(float f) {
  return (u16)((__builtin_bit_cast(u32, f) + 0x8000u) >> 16);
}
// pack two floats -> {lo16=bf(lo), hi16=bf(hi)} via one v_perm_b32
__device__ __forceinline__ u32 pkbf(float hi, float lo) {
  u32 a = __builtin_bit_cast(u32, hi) + 0x8000u;
  u32 b = __builtin_bit_cast(u32, lo) + 0x8000u;
  return __builtin_amdgcn_perm(a, b, 0x07060302u);  // {a[31:16], b[31:16]}
}

__device__ __forceinline__ v4f mfma16(bf16x8 a, bf16x8 b, v4f c) {
  return __builtin_amdgcn_mfma_f32_16x16x32_bf16(a, b, c, 0, 0, 0);
}

// async global->LDS DMA, 16B per lane; LDS dest = wave-uniform base + lane*16
__device__ __forceinline__ void gload16(const u16* g, u16* l) {
  __builtin_amdgcn_global_load_lds(
      (const __attribute__((address_space(1))) void*)g,
      (__attribute__((address_space(3))) void*)l, 16, 0, 0);
}

// ------------- kernel: fused prep --------------------------------------
// blocks [0,1728): w_qkv fp32->bf16 ; [1728,2304): w_proj ; [2304,3840):
// x (b,c,p) -> xT (b,p,c) bf16 transpose. One launch instead of three.
__global__ __launch_bounds__(256) void k_prep(const float* __restrict__ x,
                                              const float* __restrict__ wq,
                                              const float* __restrict__ wp,
                                              u16* __restrict__ xT,
                                              u16* __restrict__ wqb,
                                              u16* __restrict__ wpb) {
  __shared__ u16 Ts[64][72];   // transpose staging; pitch 72 keeps 16B align
  int bid = blockIdx.x;
  int t = threadIdx.x;
  if (bid < 2304) {
    bool isQ = bid < 1728;
    const float* s = isQ ? wq : wp;
    u16* d = isQ ? wqb : wpb;
    int i = (isQ ? bid : bid - 1728) * 256 + t;   // exact coverage, no bounds
    float4 v = ((const float4*)s)[i];
    u32 lo = (u32)f2bf(v.x) | ((u32)f2bf(v.y) << 16);
    u32 hi = (u32)f2bf(v.z) | ((u32)f2bf(v.w) << 16);
    ((uint2*)d)[i] = uint2{lo, hi};
    return;
  }
  int id = bid - 2304;
  int p0 = (id & 15) * 64; id >>= 4;
  int c0 = (id % 12) * 64; int b = id / 12;
  int cr = t >> 4;             // 0..15
  int p4 = (t & 15) * 4;       // 0..60
  const float* src = x + ((size_t)b * CDIM + c0) * NSEQ + p0;
#pragma unroll
  for (int i = 0; i < 4; ++i) {
    int c = cr + i * 16;
    float4 v = *(const float4*)&src[(size_t)c * NSEQ + p4];
    Ts[p4 + 0][c] = f2bf(v.x);
    Ts[p4 + 1][c] = f2bf(v.y);
    Ts[p4 + 2][c] = f2bf(v.z);
    Ts[p4 + 3][c] = f2bf(v.w);
  }
  __syncthreads();
  int p = t >> 2;              // 0..63
  int cq = t & 3;
  u16* dst = xT + ((size_t)b * NSEQ + p0 + p) * CDIM + c0;
#pragma unroll
  for (int j = 0; j < 2; ++j) {
    int ch = cq + j * 4;       // 8 chunks of 8 bf16 = 64 elems
    *(int4*)&dst[ch * 8] = *(const int4*)&Ts[p][ch * 8];
  }
}

// ------------- kernel: QKV GEMM  D[o][p] = sum_c W[o][c] * xT[p][c] -----
// ROUND-13 VERBATIM (measured 55.7us). 128x128 tile, 256 thr, BK=64
// single-buffer split-half K storage; 12 barrier periods.
// Q,K rows (o<1536) stored transposed qkT[b][p][o]; V rows to vbuf[b][d][p].
__global__ __launch_bounds__(256) void k_gemm_qkv(const u16* __restrict__ Wb,
                                                  const u16* __restrict__ xT,
                                                  u16* __restrict__ qkT,
                                                  u16* __restrict__ vbuf) {
  int oT = blockIdx.x * 128, pT = blockIdx.y * 128, b = blockIdx.z;
  __shared__ u16 As[2][128 * 32];   // [k-half][row*32+col] 16 KB
  __shared__ u16 Bs[2][128 * 32];   // 16 KB
  int t = threadIdx.x, lane = t & 63, wid = t >> 6;
  int ln = lane & 15, quad = lane >> 4;
  int wr = wid >> 1, wc = wid & 1;
  v4f acc[4][4] = {};

  // DMA staging: wave wid covers 16-row slabs at wid*16 and wid*16+64,
  // for each of the two 32-wide k-halves. lane i -> row +i/4, chunk (i%4)*8.
  int lr = lane >> 2, lc = (lane & 3) * 8;
  const u16* Ag = Wb + (size_t)(oT + wid * 16 + lr) * CDIM + lc;
  const u16* Bg = xT + ((size_t)b * NSEQ + pT + wid * 16 + lr) * CDIM + lc;
  int s0 = (wid * 16) * 32, s1 = (wid * 16 + 64) * 32;

  for (int kk = 0; kk < CDIM; kk += 64) {
    __syncthreads();   // all waves done reading previous slab
    gload16(Ag + kk, &As[0][s0]);
    gload16(Ag + (size_t)64 * CDIM + kk, &As[0][s1]);
    gload16(Ag + kk + 32, &As[1][s0]);
    gload16(Ag + (size_t)64 * CDIM + kk + 32, &As[1][s1]);
    gload16(Bg + kk, &Bs[0][s0]);
    gload16(Bg + (size_t)64 * CDIM + kk, &Bs[0][s1]);
    gload16(Bg + kk + 32, &Bs[1][s0]);
    gload16(Bg + (size_t)64 * CDIM + kk + 32, &Bs[1][s1]);
    __syncthreads();   // drains vmcnt (DMA) -> slab resident

    bf16x8 af0[4], af1[4], bf0[4], bf1[4];
#pragma unroll
    for (int mt = 0; mt < 4; ++mt) {
      af0[mt] = *(const bf16x8*)&As[0][(wr * 64 + mt * 16 + ln) * 32 + quad * 8];
      af1[mt] = *(const bf16x8*)&As[1][(wr * 64 + mt * 16 + ln) * 32 + quad * 8];
    }
#pragma unroll
    for (int nt = 0; nt < 4; ++nt) {
      bf0[nt] = *(const bf16x8*)&Bs[0][(wc * 64 + nt * 16 + ln) * 32 + quad * 8];
      bf1[nt] = *(const bf16x8*)&Bs[1][(wc * 64 + nt * 16 + ln) * 32 + quad * 8];
    }
#pragma unroll
    for (int mt = 0; mt < 4; ++mt)
#pragma unroll
      for (int nt = 0; nt < 4; ++nt) {
        acc[mt][nt] = mfma16(af0[mt], bf0[nt], acc[mt][nt]);
        acc[mt][nt] = mfma16(af1[mt], bf1[nt], acc[mt][nt]);
      }
  }

  bool isV = (oT >= 2 * CDIM);
#pragma unroll
  for (int mt = 0; mt < 4; ++mt) {
#pragma unroll
    for (int nt = 0; nt < 4; ++nt) {
      int ro = oT + wr * 64 + mt * 16 + quad * 4;   // 4 consecutive o rows
      int cp = pT + wc * 64 + nt * 16 + ln;
      if (!isV) {
        u32 lo = (u32)f2bf(acc[mt][nt][0]) | ((u32)f2bf(acc[mt][nt][1]) << 16);
        u32 hi = (u32)f2bf(acc[mt][nt][2]) | ((u32)f2bf(acc[mt][nt][3]) << 16);
        *(uint2*)&qkT[((size_t)b * NSEQ + cp) * 1536 + ro] = uint2{lo, hi};
      } else {
#pragma unroll
        for (int r = 0; r < 4; ++r)
          vbuf[((size_t)b * CDIM + (ro - 2 * CDIM + r)) * NSEQ + cp] =
              f2bf(acc[mt][nt][r]);
      }
    }
  }
}

// ------------- kernel: flash attention (v7) -----------------------------
// 256 thr / 4 waves, 128 queries/block, grid 768, XCD decode (id%8 = b).
// PIPELINED __syncthreads DOUBLE-BUFFER on K/V slabs (R11/R12-proj proven
// pattern): prefetch slab s+1 into alternate buffers, compute slab s, ONE
// barrier whose vmcnt-drain lands after compute. 16 barriers vs 32.
// LDS 50 KB -> still exactly 3 blocks/CU. Deterministic: every DMA<->read
// pair crosses a full-drain barrier.
__global__ __launch_bounds__(256) void k_attn(const u16* __restrict__ qkT,
                                              const u16* __restrict__ vbuf,
                                              u16* __restrict__ attnT) {
  int id = blockIdx.x;
  int b = id & 7;              // XCD slot under flat%8 round-robin
  int j = id >> 3;             // 0..95
  int h = j % 12;
  int nt0 = (j / 12) * 128;

  int t = threadIdx.x, lane = t & 63, wid = t >> 6;
  int ln = lane & 15, quad = lane >> 4;
  int nbase = nt0 + wid * 32;

  __shared__ u16 Ks[2][2][64 * 32];   // [buf][32-col half] 16 KB
  __shared__ u16 Vs[2][2][64 * 32];   // 16 KB
  __shared__ u16 Pa[4][32 * 72];      // per wave: [n][m], pitch 72; 18 KB
  u16* myP = Pa[wid];

  // Q frags (B operand of S^T): B[col=n][k]; once per kernel
  const u16* qbase = qkT + ((size_t)b * NSEQ + nbase) * 1536 + h * DH;
  bf16x8 aq[2][2];
#pragma unroll
  for (int mt = 0; mt < 2; ++mt)
#pragma unroll
    for (int ks = 0; ks < 2; ++ks)
      aq[mt][ks] = *(const bf16x8*)&qbase[(size_t)(mt * 16 + ln) * 1536 + ks * 32 + quad * 8];

  bf16x8 ones;
#pragma unroll
  for (int i = 0; i < 8; ++i) ones[i] = __builtin_bit_cast(__bf16, (u16)0x3F80);

  v4f oacc[2][4] = {};
  v4f lacc[2] = {};

  // DMA staging: wave wid covers rows wid*16..wid*16+15 of the 64-key slab.
  int lr = lane >> 2, lc = (lane & 3) * 8;
  const u16* kgw = qkT + (size_t)b * NSEQ * 1536 + CDIM + h * DH +
                   (size_t)(wid * 16 + lr) * 1536 + lc;
  const u16* vgw = vbuf + ((size_t)b * CDIM + h * DH + wid * 16 + lr) * NSEQ + lc;
  int sb = (wid * 16) * 32;   // wave-uniform LDS slab base (u16 units)

  // prologue: slab 0 -> buf 0, drain
  gload16(kgw, &Ks[0][0][sb]);
  gload16(kgw + 32, &Ks[0][1][sb]);
  gload16(vgw, &Vs[0][0][sb]);
  gload16(vgw + 32, &Vs[0][1][sb]);
  __syncthreads();

  for (int s = 0; s < 16; ++s) {
    int cur = s & 1, nxt = cur ^ 1;
    if (s < 15) {   // prefetch slab s+1 into the buffer freed at iter s-1
      size_t ko = (size_t)(s + 1) * 64 * 1536;
      int vo = (s + 1) * 64;
      gload16(kgw + ko, &Ks[nxt][0][sb]);
      gload16(kgw + ko + 32, &Ks[nxt][1][sb]);
      gload16(vgw + vo, &Vs[nxt][0][sb]);
      gload16(vgw + vo + 32, &Vs[nxt][1][sb]);
    }

    // S^T tiles (rows=keys ct, cols=queries mt); p = exp2(s*SCL)
#pragma unroll
    for (int ct = 0; ct < 4; ++ct) {
      bf16x8 kf0 = *(const bf16x8*)&Ks[cur][0][(ct * 16 + ln) * 32 + quad * 8];
      bf16x8 kf1 = *(const bf16x8*)&Ks[cur][1][(ct * 16 + ln) * 32 + quad * 8];
#pragma unroll
      for (int mt = 0; mt < 2; ++mt) {
        v4f sc = {};
        sc = mfma16(kf0, aq[mt][0], sc);
        sc = mfma16(kf1, aq[mt][1], sc);
        float p0 = __builtin_amdgcn_exp2f(sc[0] * SCL);
        float p1 = __builtin_amdgcn_exp2f(sc[1] * SCL);
        float p2 = __builtin_amdgcn_exp2f(sc[2] * SCL);
        float p3 = __builtin_amdgcn_exp2f(sc[3] * SCL);
        // lane holds P[n=mt*16+ln][m=ct*16+quad*4 .. +3] -> one 8B store
        *(uint2*)&myP[(mt * 16 + ln) * 72 + ct * 16 + quad * 4] =
            uint2{pkbf(p1, p0), pkbf(p3, p2)};
      }
    }

    // PV + row-sum: A = P (row=n, k=m), B = V (col=d, k=m) / ones
    bf16x8 ap[2][2];
#pragma unroll
    for (int mt = 0; mt < 2; ++mt)
#pragma unroll
      for (int ks = 0; ks < 2; ++ks)
        ap[mt][ks] = *(const bf16x8*)&myP[(mt * 16 + ln) * 72 + ks * 32 + quad * 8];
#pragma unroll
    for (int mt = 0; mt < 2; ++mt) {
      lacc[mt] = mfma16(ap[mt][0], ones, lacc[mt]);
      lacc[mt] = mfma16(ap[mt][1], ones, lacc[mt]);
    }
#pragma unroll
    for (int nt = 0; nt < 4; ++nt) {
      bf16x8 vf0 = *(const bf16x8*)&Vs[cur][0][(nt * 16 + ln) * 32 + quad * 8];
      bf16x8 vf1 = *(const bf16x8*)&Vs[cur][1][(nt * 16 + ln) * 32 + quad * 8];
#pragma unroll
      for (int mt = 0; mt < 2; ++mt) {
        oacc[mt][nt] = mfma16(ap[mt][0], vf0, oacc[mt][nt]);
        oacc[mt][nt] = mfma16(ap[mt][1], vf1, oacc[mt][nt]);
      }
    }
    __syncthreads();   // drains slab s+1's DMA (hidden behind compute) + joins
  }

  // normalize (lacc C-layout == oacc C-layout) and store O as attnT[b][n][c]
#pragma unroll
  for (int mt = 0; mt < 2; ++mt) {
#pragma unroll
    for (int r = 0; r < 4; ++r) {
      float inv = 1.0f / lacc[mt][r];
      int n = nbase + mt * 16 + quad * 4 + r;
      u16* dst = attnT + ((size_t)b * NSEQ + n) * CDIM + h * DH;
#pragma unroll
      for (int nt = 0; nt < 4; ++nt)
        dst[nt * 16 + ln] = b16(oacc[mt][nt][r] * inv);
    }
  }
}

// ------------- kernel: proj GEMM  out[o][p] = sum_c Wp[o][c]*attnT[p][c] -
// Grid (b, oT, pT) b-fastest (L2-resident per-batch working set).
// BK=64 single-buffer split-half (R13 qkv pattern): 12 barrier periods.
__global__ __launch_bounds__(256) void k_gemm_proj(const u16* __restrict__ Wb,
                                                   const u16* __restrict__ aT,
                                                   float* __restrict__ out) {
  int b = blockIdx.x, oT = blockIdx.y * 128, pT = blockIdx.z * 128;
  __shared__ u16 As[2][128 * 32];   // [k-half] 16 KB
  __shared__ u16 Bs[2][128 * 32];   // 16 KB
  int t = threadIdx.x, lane = t & 63, wid = t >> 6;
  int ln = lane & 15, quad = lane >> 4;
  int wr = wid >> 1, wc = wid & 1;
  v4f acc[4][4] = {};

  int lr = lane >> 2, lc = (lane & 3) * 8;
  const u16* Ag = Wb + (size_t)(oT + wid * 16 + lr) * CDIM + lc;
  const u16* Bg = aT + ((size_t)b * NSEQ + pT + wid * 16 + lr) * CDIM + lc;
  int s0 = (wid * 16) * 32, s1 = (wid * 16 + 64) * 32;

  for (int kk = 0; kk < CDIM; kk += 64) {
    __syncthreads();
    gload16(Ag + kk, &As[0][s0]);
    gload16(Ag + (size_t)64 * CDIM + kk, &As[0][s1]);
    gload16(Ag + kk + 32, &As[1][s0]);
    gload16(Ag + (size_t)64 * CDIM + kk + 32, &As[1][s1]);
    gload16(Bg + kk, &Bs[0][s0]);
    gload16(Bg + (size_t)64 * CDIM + kk, &Bs[0][s1]);
    gload16(Bg + kk + 32, &Bs[1][s0]);
    gload16(Bg + (size_t)64 * CDIM + kk + 32, &Bs[1][s1]);
    __syncthreads();

    bf16x8 af0[4], af1[4], bf0[4], bf1[4];
#pragma unroll
    for (int mt = 0; mt < 4; ++mt) {
      af0[mt] = *(const bf16x8*)&As[0][(wr * 64 + mt * 16 + ln) * 32 + quad * 8];
      af1[mt] = *(const bf16x8*)&As[1][(wr * 64 + mt * 16 + ln) * 32 + quad * 8];
    }
#pragma unroll
    for (int nt = 0; nt < 4; ++nt) {
      bf0[nt] = *(const bf16x8*)&Bs[0][(wc * 64 + nt * 16 + ln) * 32 + quad * 8];
      bf1[nt] = *(const bf16x8*)&Bs[1][(wc * 64 + nt * 16 + ln) * 32 + quad * 8];
    }
#pragma unroll
    for (int mt = 0; mt < 4; ++mt)
#pragma unroll
      for (int nt = 0; nt < 4; ++nt) {
        acc[mt][nt] = mfma16(af0[mt], bf0[nt], acc[mt][nt]);
        acc[mt][nt] = mfma16(af1[mt], bf1[nt], acc[mt][nt]);
      }
  }

#pragma unroll
  for (int mt = 0; mt < 4; ++mt) {
#pragma unroll
    for (int nt = 0; nt < 4; ++nt) {
      int ro = oT + wr * 64 + mt * 16 + quad * 4;
      int cp = pT + wc * 64 + nt * 16 + ln;
#pragma unroll
      for (int r = 0; r < 4; ++r)
        out[((size_t)b * CDIM + ro + r) * NSEQ + cp] = acc[mt][nt][r];
    }
  }
}

extern "C" void kernel_launch(void* const* d_in, const int* in_sizes, int n_in,
                              void* d_out, int out_size, void* d_ws, size_t ws_size,
                              hipStream_t stream) {
  const float* x = (const float*)d_in[0];
  const float* w_qkv = (const float*)d_in[1];
  const float* w_proj = (const float*)d_in[2];
  float* out = (float*)d_out;

  char* ws = (char*)d_ws;
  // ws layout (bytes):
  //   wqkv_bf : 2304*768*2       = 3,538,944
  //   wproj_bf: 768*768*2        = 1,179,648
  //   xT      : 8*1024*768*2     = 12,582,912   (reused as attnT after GEMM1)
  //   vbuf    : 8*768*1024*2     = 12,582,912
  // qkT (8*1024*1536*2 = 25,165,824 B) aliases d_out (8*768*1024*4 = same size);
  // qkT is dead before k_gemm_proj writes d_out.
  u16* wqkv_bf = (u16*)(ws);
  u16* wproj_bf = (u16*)(ws + 3538944);
  u16* xT = (u16*)(ws + 4718592);
  u16* vbuf = (u16*)(ws + 17301504);
  u16* qkT = (u16*)d_out;
  u16* attnT = xT;

  k_prep<<<dim3(3840), dim3(256), 0, stream>>>(x, w_qkv, w_proj, xT, wqkv_bf, wproj_bf);
  k_gemm_qkv<<<dim3(18, 8, 8), dim3(256), 0, stream>>>(wqkv_bf, xT, qkT, vbuf);
  k_attn<<<dim3(768), dim3(256), 0, stream>>>(qkT, vbuf, attnT);
  k_gemm_proj<<<dim3(8, 6, 8), dim3(256), 0, stream>>>(wproj_bf, attnT, out);
}